// Round 13
// baseline (512.708 us; speedup 1.0000x reference)
//
#include <hip/hip_runtime.h>
#include <hip/hip_bf16.h>

// Dual-stage topic attention. f32 I/O, bf16 intermediates.
//   Xb = bf16(x); Wb* = bf16(W*)
//   Mx = segmean(x);  Mq = Mx @ Wqc^T + bq2   (Wqc = Wq + Wq@Wc,
//       bq2 = Wq*bc — M-path is linear, Mb never materialized)
//   [Q|K|V] = Xb @ [Wq|Wk|Wv]^T + bias
//   T = Q + Mq[seg] (on the fly)
//   VT = attn(T,K,V) -> d_out[0:half) ; CTX = attn(Q,T,VT) -> K slot
//   out = CTX @ Wo^T + bo (f32)
// r25 = r24 (best, 388.3us) + ONE attn change: each block processes TWO
// q-tiles (rows p*256+w*32 and +128) against each staged K/V tile.
// Mechanism: the 4 q-tile blocks of one (b,h) re-staged identical K/V
// every iter (4x redundant LDS staging + global K/V reads); doubling
// compute per stage halves the staging fraction and K/V traffic, and
// grid 1536->768 = ONE full-resident round at __launch_bounds__(256,3)
// (vs 1.5 ragged rounds at 4/CU). Pl reused sequentially per warp
// (in-warp LDS ordering; no extra barrier). Watch: VGPR ~170, no scratch.
// k_front/k_mid/wo byte-identical to r24.

typedef __bf16 bf16_t;
typedef __bf16 bf16x8 __attribute__((ext_vector_type(8)));
typedef __bf16 bf16x4 __attribute__((ext_vector_type(4)));
typedef float f32x4 __attribute__((ext_vector_type(4)));

#define B_ 32
#define N_ 512
#define D_ 768
#define H_ 12
#define HD_ 64
#define K_ 8
#define ND_ (N_ * D_)   // 393216

typedef __attribute__((address_space(1))) unsigned int as1_u32;
typedef __attribute__((address_space(3))) unsigned int as3_u32;

__device__ __forceinline__ void glds16(const void* g, void* l) {
  // async global->LDS, 16B/lane; LDS dest = wave-uniform base + lane*16
  __builtin_amdgcn_global_load_lds((as1_u32*)g, (as3_u32*)l, 16, 0, 0);
}

__device__ __forceinline__ f32x4 mfma16(bf16x8 a, bf16x8 b, f32x4 c) {
  return __builtin_amdgcn_mfma_f32_16x16x32_bf16(a, b, c, 0, 0, 0);
}

__device__ __forceinline__ bf16x8 addv8(bf16x8 a, bf16x8 b) {
  bf16x8 o;
#pragma unroll
  for (int j = 0; j < 8; ++j) o[j] = (bf16_t)((float)a[j] + (float)b[j]);
  return o;
}

// tid int32 or int64; int64 => word[1] (high half of elem0) == 0 (values 1..8).
__device__ __forceinline__ int seg_of(const int* tid, int b) {
  const bool is64 = (tid[1] == 0);
  int v = is64 ? (int)((const long long*)tid)[b] : tid[b];
  return v - 1;
}

// ---------------------------------------------------------------------------
// GEMM core (pure bf16, r13-verified): C[128x128] = A[128xK] * B^T[128xK],
// K=768, BK=32. Async glds staging, double-buffered, ONE barrier per K-iter.
// ---------------------------------------------------------------------------
__device__ __forceinline__ void gemm_core(const bf16_t* __restrict__ A,
                                          const bf16_t* __restrict__ Bw,
                                          char* smem, f32x4 (&acc)[4][4]) {
  const int t = threadIdx.x;
  const int lane = t & 63, w = t >> 6;
  const int quad = lane >> 4, l15 = lane & 15;
  const int r0 = t >> 2;         // staging row (chunk t); chunk t+256: +64
  const int c0e = (t & 3) * 8;   // staging k-element offset
  const int wbase = w * 1024;    // wave-uniform LDS base within a 4KB half
  const int mRow = (w >> 1) * 64, nCol = (w & 1) * 64;

  const bf16_t* ga0 = A + (size_t)r0 * D_ + c0e;
  const bf16_t* ga1 = A + (size_t)(r0 + 64) * D_ + c0e;
  const bf16_t* gb0 = Bw + (size_t)r0 * D_ + c0e;
  const bf16_t* gb1 = Bw + (size_t)(r0 + 64) * D_ + c0e;

  // preload iter 0 into buffer 0
  glds16(ga0, smem + wbase);
  glds16(ga1, smem + 4096 + wbase);
  glds16(gb0, smem + 8192 + wbase);
  glds16(gb1, smem + 12288 + wbase);

  for (int kb = 0; kb < 24; ++kb) {
    __syncthreads();  // vmcnt(0) drain: iter-kb glds complete; prev reads done
    char* cur = smem + (kb & 1) * 16384;
    char* nxt = smem + ((kb + 1) & 1) * 16384;
    if (kb < 23) {  // async-stage next slice; in flight during MFMA below
      const int ko = (kb + 1) * 32;
      glds16(ga0 + ko, nxt + wbase);
      glds16(ga1 + ko, nxt + 4096 + wbase);
      glds16(gb0 + ko, nxt + 8192 + wbase);
      glds16(gb1 + ko, nxt + 12288 + wbase);
    }
    bf16x8 af[4], bfr[4];
#pragma unroll
    for (int mt = 0; mt < 4; ++mt)
      af[mt] = *(const bf16x8*)(cur + (mRow + mt * 16 + l15) * 64 + quad * 16);
#pragma unroll
    for (int nt = 0; nt < 4; ++nt)
      bfr[nt] = *(const bf16x8*)(cur + 8192 + (nCol + nt * 16 + l15) * 64 +
                                 quad * 16);
#pragma unroll
    for (int mt = 0; mt < 4; ++mt)
#pragma unroll
      for (int nt = 0; nt < 4; ++nt)
        acc[mt][nt] = mfma16(af[mt], bfr[nt], acc[mt][nt]);
  }
}

__device__ __forceinline__ void zero_acc(f32x4 (&acc)[4][4]) {
  const f32x4 z = {0.f, 0.f, 0.f, 0.f};
#pragma unroll
  for (int a = 0; a < 4; ++a)
#pragma unroll
    for (int b = 0; b < 4; ++b) acc[a][b] = z;
}

// ---------------------------------------------------------------------------
// k_front roles (order = longest chain first):
//   blocks 0-35   : Wqc = Wq + Wq@Wc (f32 in, bf16 out; reg-staged MFMA,
//                   B=Wc staged TRANSPOSED through LDS; DOUBLE-buffered
//                   2x16KB, ONE barrier/iter; 6x6 tiles of 128^2, K=768)
//   blocks 36-38  : bq2[e] = sum_d Wq[e][d]*bc[d]  (f32)
//   blocks 39-230 : segmean + Xb emit
//   blocks 231-950: cvt of the 5 weight matrices (144 blocks each, 2x data)
// ---------------------------------------------------------------------------
__global__ __launch_bounds__(256) void k_front(
    const float* __restrict__ x, const float* __restrict__ Wq,
    const float* __restrict__ Wk, const float* __restrict__ Wv,
    const float* __restrict__ Wc, const float* __restrict__ Wo,
    const float* __restrict__ bc, const int* __restrict__ tid,
    bf16_t* __restrict__ Xb, bf16_t* __restrict__ Wqb,
    bf16_t* __restrict__ Wkb, bf16_t* __restrict__ Wvb,
    bf16_t* __restrict__ Wcb, bf16_t* __restrict__ Wob,
    bf16_t* __restrict__ Mx, bf16_t* __restrict__ Wqcb,
    float* __restrict__ bq2) {
  __shared__ alignas(16) char smem[32768];
  const int t = threadIdx.x;

  if (blockIdx.x < 36) {
    // ---- Wqc role: C[e][c] = sum_d Wq[e][d]*Wc[d][c]; out bf16(C + Wq) ----
    const int mblk = blockIdx.x / 6, nblk = blockIdx.x % 6;
    const int lane = t & 63, w = t >> 6;
    const int quad = lane >> 4, l15 = lane & 15;
    const int mRow = (w >> 1) * 64, nCol = (w & 1) * 64;
    const int ar = t >> 2, ac = (t & 3) * 8;
    const int bd = t >> 3, bc0 = (t & 7) * 16;
    const float* gA0 = Wq + (size_t)(mblk * 128 + ar) * D_ + ac;
    const float* gA1 = gA0 + (size_t)64 * D_;
    const float* gB = Wc + (size_t)bd * D_ + nblk * 128 + bc0;

    f32x4 a0[2], a1[2], bv[4];
    auto loadt = [&](int kb) {
      const int ko = kb * 32;
      a0[0] = *(const f32x4*)(gA0 + ko);
      a0[1] = *(const f32x4*)(gA0 + ko + 4);
      a1[0] = *(const f32x4*)(gA1 + ko);
      a1[1] = *(const f32x4*)(gA1 + ko + 4);
      const float* pb = gB + (size_t)ko * D_;
#pragma unroll
      for (int j = 0; j < 4; ++j) bv[j] = *(const f32x4*)(pb + j * 4);
    };
    auto writeb = [&](char* buf) {
      bf16x8 av0, av1;
#pragma unroll
      for (int j = 0; j < 4; ++j) {
        av0[j] = (bf16_t)a0[0][j]; av0[4 + j] = (bf16_t)a0[1][j];
        av1[j] = (bf16_t)a1[0][j]; av1[4 + j] = (bf16_t)a1[1][j];
      }
      *(bf16x8*)(buf + ar * 64 + (t & 3) * 16) = av0;
      *(bf16x8*)(buf + 4096 + ar * 64 + (t & 3) * 16) = av1;
      bf16_t* bl = (bf16_t*)(buf + 8192);
#pragma unroll
      for (int j = 0; j < 4; ++j)
#pragma unroll
        for (int jj = 0; jj < 4; ++jj)
          bl[(bc0 + j * 4 + jj) * 32 + bd] = (bf16_t)bv[j][jj];
    };

    f32x4 acc[4][4];
    zero_acc(acc);
    loadt(0);
    writeb(smem);      // buf0 <- tile 0
    loadt(1);          // regs <- tile 1
    __syncthreads();   // buf0 visible to all

    for (int kb = 0; kb < 24; ++kb) {
      char* cur = smem + (kb & 1) * 16384;
      if (kb < 23) {
        writeb(smem + ((kb + 1) & 1) * 16384);  // nxt <- tile kb+1 (regs);
        // safe: reads of nxt (iter kb-1) retired before the barrier crossed
        if (kb < 22) loadt(kb + 2);             // regs <- tile kb+2
      }
      bf16x8 af[4], bfr[4];
#pragma unroll
      for (int mt = 0; mt < 4; ++mt)
        af[mt] = *(const bf16x8*)(cur + (mRow + mt * 16 + l15) * 64 +
                                  quad * 16);
#pragma unroll
      for (int nt = 0; nt < 4; ++nt)
        bfr[nt] = *(const bf16x8*)(cur + 8192 + (nCol + nt * 16 + l15) * 64 +
                                   quad * 16);
#pragma unroll
      for (int mt = 0; mt < 4; ++mt)
#pragma unroll
        for (int nt = 0; nt < 4; ++nt)
          acc[mt][nt] = mfma16(af[mt], bfr[nt], acc[mt][nt]);
      if (kb < 23) __syncthreads();  // retire cur reads; nxt writes visible
    }
    const int mbase = mblk * 128 + mRow;
    const int nbase = nblk * 128 + nCol;
#pragma unroll
    for (int nt = 0; nt < 4; ++nt) {
      const int col = nbase + nt * 16 + l15;
#pragma unroll
      for (int mt = 0; mt < 4; ++mt)
#pragma unroll
        for (int r = 0; r < 4; ++r) {
          const int row = mbase + mt * 16 + quad * 4 + r;
          const size_t oi = (size_t)row * D_ + col;
          Wqcb[oi] = (bf16_t)(acc[mt][nt][r] + Wq[oi]);  // + identity term
        }
    }
    return;
  }

  if (blockIdx.x < 39) {
    // ---- bq2 role: bq2[e] = sum_d Wq[e][d] * bc[d] (f32) ----
    const int e = (blockIdx.x - 36) * 256 + t;
    const float* wr = Wq + (size_t)e * D_;
    float s = 0.f;
    for (int d = 0; d < D_; d += 4) {
      f32x4 wv = *(const f32x4*)(wr + d);
      f32x4 bv = *(const f32x4*)(bc + d);
#pragma unroll
      for (int j = 0; j < 4; ++j) s += wv[j] * bv[j];
    }
    bq2[e] = s;
    return;
  }

  if (blockIdx.x < 231) {
    // ---- segmean + Xb emit ----
    const size_t i = ((size_t)(blockIdx.x - 39) * 256 + t) * 8;
    float acc[K_][8];
    float cntk[K_];
#pragma unroll
    for (int k = 0; k < K_; ++k) {
      cntk[k] = 0.f;
#pragma unroll
      for (int j = 0; j < 8; ++j) acc[k][j] = 0.f;
    }
    const bool is64 = (tid[1] == 0);
    for (int b = 0; b < B_; ++b) {
      const int s = (is64 ? (int)((const long long*)tid)[b] : tid[b]) - 1;
      const float* p = x + (size_t)b * ND_ + i;
      f32x4 y0 = *(const f32x4*)p;
      f32x4 y1 = *(const f32x4*)(p + 4);
      bf16x8 xo;
#pragma unroll
      for (int j = 0; j < 4; ++j) {
        xo[j] = (bf16_t)y0[j];
        xo[4 + j] = (bf16_t)y1[j];
      }
      *(bf16x8*)(Xb + (size_t)b * ND_ + i) = xo;  // fused cvt-X
#pragma unroll
      for (int k = 0; k < K_; ++k) {
        const float msk = (s == k) ? 1.f : 0.f;
        cntk[k] += msk;
#pragma unroll
        for (int j = 0; j < 4; ++j) {
          acc[k][j] += msk * y0[j];
          acc[k][4 + j] += msk * y1[j];
        }
      }
    }
#pragma unroll
    for (int k = 0; k < K_; ++k) {
      const float inv = 1.f / fmaxf(cntk[k], 1.f);
      bf16x8 o;
#pragma unroll
      for (int j = 0; j < 8; ++j) o[j] = (bf16_t)(acc[k][j] * inv);
      *(bf16x8*)(Mx + (size_t)k * ND_ + i) = o;
    }
    return;
  }
  // ---- weight cvt role (2x data per block: 144 blocks per matrix) ----
  int bid = blockIdx.x - 231;
  const int wi = bid / 144;
  bid = bid % 144;
  const float* in = wi == 0 ? Wq : wi == 1 ? Wk : wi == 2 ? Wv : wi == 3 ? Wc
                                                                         : Wo;
  bf16_t* out = wi == 0 ? Wqb : wi == 1 ? Wkb : wi == 2 ? Wvb : wi == 3 ? Wcb
                                                                        : Wob;
  const size_t i = ((size_t)bid * 256 + t) * 16;
#pragma unroll
  for (int h = 0; h < 2; ++h) {
    f32x4 a = *(const f32x4*)(in + i + h * 8);
    f32x4 b = *(const f32x4*)(in + i + h * 8 + 4);
    bf16x8 o;
#pragma unroll
    for (int j = 0; j < 4; ++j) {
      o[j] = (bf16_t)a[j];
      o[4 + j] = (bf16_t)b[j];
    }
    *(bf16x8*)(out + i + h * 8) = o;
  }
}

// ---------------------------------------------------------------------------
// k_mid: blocks 0-191 = Mq-role (Mq = Mx@Wqc^T + bq2, bf16 out, starts
//        first — its 24-iter latency chain hides under qkv);
//        blocks 192-2495 = fused QKV GEMM, r13-exact mapping on bid-192
//        (XCD-swizzled: 18 tiles of one X row-block on ONE XCD).
// __launch_bounds__(256,4): 4 blocks/CU (r22-measured win).
// ---------------------------------------------------------------------------
__global__ __launch_bounds__(256, 4) void k_mid(
    const bf16_t* __restrict__ X, const bf16_t* __restrict__ Wq,
    const bf16_t* __restrict__ Wk, const bf16_t* __restrict__ Wv,
    const float* __restrict__ bq, const float* __restrict__ bk,
    const float* __restrict__ bv, bf16_t* __restrict__ Q,
    bf16_t* __restrict__ Kb, bf16_t* __restrict__ V,
    const bf16_t* __restrict__ Mx, const bf16_t* __restrict__ Wqcb,
    const float* __restrict__ bq2, bf16_t* __restrict__ Mq) {
  __shared__ alignas(16) char smem[32768];
  const int lane = threadIdx.x & 63, w = threadIdx.x >> 6;
  const int quad = lane >> 4, l15 = lane & 15;

  if (blockIdx.x < 192) {
    // ---- Mq role: Mq = Mx @ Wqcb^T + bq2 ----
    const int mblk = blockIdx.x / 6, nblk = blockIdx.x % 6;
    f32x4 acc[4][4];
    zero_acc(acc);
    gemm_core(Mx + (size_t)mblk * 128 * D_, Wqcb + (size_t)nblk * 128 * D_,
              smem, acc);
    const int mbase = mblk * 128 + (w >> 1) * 64;
    const int nbase = nblk * 128 + (w & 1) * 64;
#pragma unroll
    for (int nt = 0; nt < 4; ++nt) {
      const int col = nbase + nt * 16 + l15;
      const float bb = bq2[col];
#pragma unroll
      for (int mt = 0; mt < 4; ++mt)
#pragma unroll
        for (int r = 0; r < 4; ++r) {
          const int row = mbase + mt * 16 + quad * 4 + r;
          Mq[(size_t)row * D_ + col] = (bf16_t)(acc[mt][nt][r] + bb);
        }
    }
    return;
  }

  // ---- QKV role (r13-exact on qbid) ----
  const int qbid = blockIdx.x - 192;
  const int xcd = qbid & 7, i = qbid >> 3;
  const int tile = i % 18, rowblk = (i / 18) * 8 + xcd;
  const int wsel = tile / 6, nb = tile % 6;
  const bf16_t* W = wsel == 0 ? Wq : wsel == 1 ? Wk : Wv;
  const float* bias = wsel == 0 ? bq : wsel == 1 ? bk : bv;
  bf16_t* Out = wsel == 0 ? Q : wsel == 1 ? Kb : V;

  f32x4 acc[4][4];
  zero_acc(acc);
  gemm_core(X + (size_t)rowblk * 128 * D_, W + (size_t)nb * 128 * D_, smem,
            acc);

  const int mbase = rowblk * 128 + (w >> 1) * 64;
  const int nbase = nb * 128 + (w & 1) * 64;
#pragma unroll
  for (int nt = 0; nt < 4; ++nt) {
    const int col = nbase + nt * 16 + l15;
    const float bb = bias[col];
#pragma unroll
    for (int mt = 0; mt < 4; ++mt)
#pragma unroll
      for (int r = 0; r < 4; ++r) {
        const int row = mbase + mt * 16 + quad * 4 + r;
        Out[(size_t)row * D_ + col] = (bf16_t)(acc[mt][nt][r] + bb);
      }
  }
}

// Plain GEMM: Out[Mx768] = A(bf16) @ W(bf16)^T (+bias f32) (+addA bf16).
// swz=1: flat grid M/128*6 blocks, XCD-swizzled. swz=0: 2D grid (M/128, 6).
__global__ __launch_bounds__(256) void k_gemm_plain(
    const bf16_t* __restrict__ A, const bf16_t* __restrict__ W,
    const float* __restrict__ bias, const bf16_t* __restrict__ addA,
    void* __restrict__ Out, int outF32, int swz) {
  __shared__ alignas(16) char smem[32768];
  int mblk, nblk;
  if (swz) {
    const int bid = blockIdx.x;
    const int xcd = bid & 7, i = bid >> 3;
    nblk = i % 6;
    mblk = (i / 6) * 8 + xcd;
  } else {
    mblk = blockIdx.x;
    nblk = blockIdx.y;
  }
  f32x4 acc[4][4];
  zero_acc(acc);
  gemm_core(A + (size_t)mblk * 128 * D_, W + (size_t)nblk * 128 * D_, smem,
            acc);
  const int lane = threadIdx.x & 63, w = threadIdx.x >> 6;
  const int quad = lane >> 4, l15 = lane & 15;
  const int mbase = mblk * 128 + (w >> 1) * 64;
  const int nbase = nblk * 128 + (w & 1) * 64;
#pragma unroll
  for (int nt = 0; nt < 4; ++nt) {
    const int col = nbase + nt * 16 + l15;
    const float bb = bias ? bias[col] : 0.f;
#pragma unroll
    for (int mt = 0; mt < 4; ++mt)
#pragma unroll
      for (int r = 0; r < 4; ++r) {
        const int row = mbase + mt * 16 + quad * 4 + r;
        float v = acc[mt][nt][r] + bb;
        if (addA) v += (float)addA[(size_t)row * D_ + col];
        const size_t oi = (size_t)row * D_ + col;
        if (outF32) ((float*)Out)[oi] = v;
        else ((bf16_t*)Out)[oi] = (bf16_t)v;
      }
  }
}

// ---------------------------------------------------------------------------
// Flash attention per (b,h): Out = softmax(Q' @ K'^T / 8) @ V
//   addq==1: queries = Qp + Madd[seg];  addq==2: keys = Kp + Madd[seg]
// r25: TWO q-tiles per block (qA = blockIdx.x*256 + w*32, qB = qA+128)
// against each staged K/V tile — staging/iter unchanged, compute doubled,
// K/V global reads halved, grid (2,B*H)=768 all-resident at 3 blocks/CU.
// Pl reused sequentially per warp (in-warp LDS ordering, no extra barrier).
// ---------------------------------------------------------------------------
__global__ __launch_bounds__(256, 3) void k_attn(
    const bf16_t* __restrict__ Qp, const bf16_t* __restrict__ Kp,
    const bf16_t* __restrict__ Vp, const bf16_t* __restrict__ Madd,
    const int* __restrict__ tid, bf16_t* __restrict__ Op, int addq) {
  __shared__ alignas(16) __bf16 Kt[64][72];
  __shared__ alignas(16) __bf16 Vt[64][72];
  __shared__ alignas(16) __bf16 Pl[4][32][72];

  const int lane = threadIdx.x & 63, w = threadIdx.x >> 6;
  const int quad = lane >> 4, l15 = lane & 15;
  const int b = blockIdx.y / H_, h = blockIdx.y % H_;
  const int qA = blockIdx.x * 256 + w * 32;  // tile A rows; tile B = +128
  const size_t base = (size_t)b * ND_ + h * HD_;
  const float C = 0.18033688011112042f;  // log2(e) / sqrt(HD)
  const int sg = seg_of(tid, b);
  const bf16_t* Mh = Madd + (size_t)sg * ND_ + h * HD_;

  bf16x8 aqA[2][2], aqB[2][2];
#pragma unroll
  for (int mt = 0; mt < 2; ++mt)
#pragma unroll
    for (int ks = 0; ks < 2; ++ks) {
      const size_t offA =
          (size_t)(qA + mt * 16 + l15) * D_ + ks * 32 + quad * 8;
      const size_t offB = offA + (size_t)128 * D_;
      bf16x8 q = *(const bf16x8*)(Qp + base + offA);
      if (addq == 1) q = addv8(q, *(const bf16x8*)(Mh + offA));
      aqA[mt][ks] = q;
      q = *(const bf16x8*)(Qp + base + offB);
      if (addq == 1) q = addv8(q, *(const bf16x8*)(Mh + offB));
      aqB[mt][ks] = q;
    }

  f32x4 OA[2][4], OB[2][4];
  float laccA[2][4], laccB[2][4];
  {
    const f32x4 z = {0.f, 0.f, 0.f, 0.f};
#pragma unroll
    for (int mt = 0; mt < 2; ++mt)
#pragma unroll
      for (int nt = 0; nt < 4; ++nt) { OA[mt][nt] = z; OB[mt][nt] = z; }
#pragma unroll
    for (int mt = 0; mt < 2; ++mt)
#pragma unroll
      for (int r = 0; r < 4; ++r) { laccA[mt][r] = 0.f; laccB[mt][r] = 0.f; }
  }

  const int sr = threadIdx.x >> 2, sc = threadIdx.x & 3;
  const int sig_sr = ((sr & 15) << 2) | (sr >> 4);  // sigma-permuted V column

  bf16x8 kr[2], vr[2];
#pragma unroll
  for (int half = 0; half < 2; ++half) {
    const int cc = sc + half * 4;
    const size_t off = (size_t)sr * D_ + cc * 8;
    bf16x8 kv = *(const bf16x8*)(Kp + base + off);
    if (addq == 2) kv = addv8(kv, *(const bf16x8*)(Mh + off));
    kr[half] = kv;
    vr[half] = *(const bf16x8*)(Vp + base + off);
  }

  for (int c0 = 0; c0 < N_; c0 += 64) {
    __syncthreads();
#pragma unroll
    for (int half = 0; half < 2; ++half) {
      const int cc = sc + half * 4;
      *(bf16x8*)(&Kt[sr][cc * 8]) = kr[half];
#pragma unroll
      for (int j = 0; j < 8; ++j) Vt[cc * 8 + j][sig_sr] = vr[half][j];
    }
    __syncthreads();

    if (c0 + 64 < N_) {
#pragma unroll
      for (int half = 0; half < 2; ++half) {
        const int cc = sc + half * 4;
        const size_t off = (size_t)(c0 + 64 + sr) * D_ + cc * 8;
        bf16x8 kv = *(const bf16x8*)(Kp + base + off);
        if (addq == 2) kv = addv8(kv, *(const bf16x8*)(Mh + off));
        kr[half] = kv;
        vr[half] = *(const bf16x8*)(Vp + base + off);
      }
    }

    // ---- tile A then tile B (sequential, same staged K/V, Pl reused) ----
#pragma unroll
    for (int tb = 0; tb < 2; ++tb) {
      f32x4 S[2][4];
      {
        const f32x4 z = {0.f, 0.f, 0.f, 0.f};
#pragma unroll
        for (int mt = 0; mt < 2; ++mt)
#pragma unroll
          for (int nt = 0; nt < 4; ++nt) S[mt][nt] = z;
      }
#pragma unroll
      for (int ks = 0; ks < 2; ++ks) {
        bf16x8 bk[4];
#pragma unroll
        for (int nt = 0; nt < 4; ++nt)
          bk[nt] = *(const bf16x8*)(&Kt[nt * 16 + l15][ks * 32 + quad * 8]);
#pragma unroll
        for (int mt = 0; mt < 2; ++mt)
#pragma unroll
          for (int nt = 0; nt < 4; ++nt)
            S[mt][nt] = mfma16(tb ? aqB[mt][ks] : aqA[mt][ks], bk[nt],
                               S[mt][nt]);
      }

#pragma unroll
      for (int mt = 0; mt < 2; ++mt)
#pragma unroll
        for (int r = 0; r < 4; ++r) {
          bf16x4 pk;
#pragma unroll
          for (int nt = 0; nt < 4; ++nt) {
            const float p = exp2f(S[mt][nt][r] * C);
            if (tb) laccB[mt][r] += p; else laccA[mt][r] += p;
            pk[nt] = (bf16_t)p;
          }
          *(bf16x4*)(&Pl[w][mt * 16 + quad * 4 + r][l15 * 4]) = pk;
        }

#pragma unroll
      for (int ks2 = 0; ks2 < 2; ++ks2) {
        bf16x8 ap[2], bv[4];
#pragma unroll
        for (int mt = 0; mt < 2; ++mt)
          ap[mt] =
              *(const bf16x8*)(&Pl[w][mt * 16 + l15][ks2 * 32 + quad * 8]);
#pragma unroll
        for (int nt2 = 0; nt2 < 4; ++nt2)
          bv[nt2] =
              *(const bf16x8*)(&Vt[nt2 * 16 + l15][ks2 * 32 + quad * 8]);
#pragma unroll
        for (int mt = 0; mt < 2; ++mt)
#pragma unroll
          for (int nt2 = 0; nt2 < 4; ++nt2) {
            if (tb)
              OB[mt][nt2] = mfma16(ap[mt], bv[nt2], OB[mt][nt2]);
            else
              OA[mt][nt2] = mfma16(ap[mt], bv[nt2], OA[mt][nt2]);
          }
      }
    }
  }

#pragma unroll
  for (int tb = 0; tb < 2; ++tb)
#pragma unroll
    for (int mt = 0; mt < 2; ++mt)
#pragma unroll
      for (int r = 0; r < 4; ++r) {
        float l = tb ? laccB[mt][r] : laccA[mt][r];
#pragma unroll
        for (int d = 1; d < 16; d <<= 1) l += __shfl_xor(l, d);
        const float inv = 1.f / l;
        const size_t row =
            base + (size_t)(qA + tb * 128 + mt * 16 + quad * 4 + r) * D_;
#pragma unroll
        for (int nt2 = 0; nt2 < 4; ++nt2) {
          const f32x4& o = tb ? OB[mt][nt2] : OA[mt][nt2];
          Op[row + nt2 * 16 + l15] = (bf16_t)(o[r] * inv);
        }
      }
}

// Fallback: zero d_out (f32 extent). Fingerprint: absmax == max|ref|.
__global__ __launch_bounds__(256) void k_zero(float* __restrict__ out) {
  const size_t i = ((size_t)blockIdx.x * 256 + threadIdx.x) * 8;
  f32x4 z = {0.f, 0.f, 0.f, 0.f};
  *(f32x4*)(out + i) = z;
  *(f32x4*)(out + i + 4) = z;
}

// ---------------------------------------------------------------------------
extern "C" void kernel_launch(void* const* d_in, const int* in_sizes, int n_in,
                              void* d_out, int out_size, void* d_ws,
                              size_t ws_size, hipStream_t stream) {
  const float* x  = (const float*)d_in[0];
  const int*  tid = (const int*)d_in[1];
  const float* Wq = (const float*)d_in[2];
  const float* bq = (const float*)d_in[3];
  const float* Wk = (const float*)d_in[4];
  const float* bk = (const float*)d_in[5];
  const float* Wv = (const float*)d_in[6];
  const float* bv = (const float*)d_in[7];
  const float* Wo = (const float*)d_in[8];
  const float* bo = (const float*)d_in[9];
  const float* Wc = (const float*)d_in[10];
  const float* bc = (const float*)d_in[11];

  const size_t SZ  = (size_t)B_ * ND_ * sizeof(bf16_t);   // 25165824
  const size_t MSZ = (size_t)K_ * ND_ * sizeof(bf16_t);   // 6291456
  const size_t WSZ = (size_t)D_ * D_ * sizeof(bf16_t);    // 1179648
  if (ws_size < 3 * SZ + MSZ + 5 * WSZ) {  // diagnosable fallback
    k_zero<<<6144, 256, 0, stream>>>((float*)d_out);
    return;
  }

  char* ws = (char*)d_ws;
  bf16_t* Qb  = (bf16_t*)(ws);
  bf16_t* Kb  = (bf16_t*)(ws + SZ);
  bf16_t* Vb  = (bf16_t*)(ws + 2 * SZ);
  bf16_t* Mq  = (bf16_t*)(ws + 3 * SZ);
  bf16_t* Wqb = (bf16_t*)(ws + 3 * SZ + MSZ);
  bf16_t* Wkb = (bf16_t*)(ws + 3 * SZ + MSZ + WSZ);
  bf16_t* Wvb = (bf16_t*)(ws + 3 * SZ + MSZ + 2 * WSZ);
  bf16_t* Wcb = (bf16_t*)(ws + 3 * SZ + MSZ + 3 * WSZ);
  bf16_t* Wob = (bf16_t*)(ws + 3 * SZ + MSZ + 4 * WSZ);
  // merge-safe aliasing (all in d_out's first half = VT region, dead
  // before attn1 writes VT):
  bf16_t* Wqcb = (bf16_t*)d_out;                             // [0, 1.2MB)
  float*  bq2  = (float*)((char*)d_out + 2 * 1024 * 1024);   // [2MB, +3KB)
  bf16_t* Mx   = (bf16_t*)((char*)d_out + 8 * 1024 * 1024);  // [8, 14.3MB)
  bf16_t* VT   = (bf16_t*)d_out;   // bf16 scratch: first half of d_out
  bf16_t* Xb   = (bf16_t*)d_out + (size_t)B_ * ND_;  // second half of d_out
  bf16_t* CTX  = Kb;               // K dead after stage-1 attention

  // 1) Wqc (0-35) + bq2 (36-38) + segmean+XbEmit (39-230) + wcvt (231-950)
  k_front<<<951, 256, 0, stream>>>(x, Wq, Wk, Wv, Wc, Wo, bc, tid, Xb, Wqb,
                                   Wkb, Wvb, Wcb, Wob, Mx, Wqcb, bq2);
  // 2) Mq = Mx@Wqc^T + bq2 (blocks 0-191) + QKV (192-2495)
  k_mid<<<2496, 256, 0, stream>>>(Xb, Wqb, Wkb, Wvb, bq, bk, bv, Qb, Kb, Vb,
                                  Mx, Wqcb, bq2, Mq);
  // 3,4) dual-stage attention (2 q-tiles per block)
  k_attn<<<dim3(2, B_ * H_), 256, 0, stream>>>(Qb, Kb, Vb, Mq, tid, VT, 1);
  k_attn<<<dim3(2, B_ * H_), 256, 0, stream>>>(Qb, Qb, VT, Mq, tid, CTX, 2);
  // 5) out = CTX @ Wo^T + bo
  k_gemm_plain<<<768, 256, 0, stream>>>(CTX, Wob, bo, nullptr, d_out, 1, 1);
}

// Round 14
// 386.431 us; speedup vs baseline: 1.3268x; 1.3268x over previous
//
#include <hip/hip_runtime.h>
#include <hip/hip_bf16.h>

// Dual-stage topic attention. f32 I/O, bf16 intermediates.
//   Xb = bf16(x); Wb* = bf16(W*)
//   Mx = segmean(x);  Mq = Mx @ Wqc^T + bq2   (Wqc = Wq + Wq@Wc,
//       bq2 = Wq*bc — M-path is linear, Mb never materialized)
//   [Q|K|V] = Xb @ [Wq|Wk|Wv]^T + bias
//   T = Q + Mq[seg] (on the fly)
//   VT = attn(T,K,V) -> d_out[0:half) ; CTX = attn(Q,T,VT) -> K slot
//   out = CTX @ Wo^T + bo (f32)
// r26 = r24 (verified best, 388.3us) + dead-work deletion. r25 post-mortem:
// 2-q-tile attn SPILLED (VGPR 84 + scratch: hbm_bytes 572MB/dispatch vs
// ~75 ideal, MfmaUtil 7.7%, attn 90->132us) — attn reverted to r13-exact
// (grid (4,B*H)); attn is CLOSED (4 structural levers all null/negative).
// Dead work: Wcb (bf16 Wc) is never read since the r23 algebraic fold —
// its cvt role (144 blocks) deleted; k_front grid 951 -> 807.
// Everything else byte-identical to r24.

typedef __bf16 bf16_t;
typedef __bf16 bf16x8 __attribute__((ext_vector_type(8)));
typedef __bf16 bf16x4 __attribute__((ext_vector_type(4)));
typedef float f32x4 __attribute__((ext_vector_type(4)));

#define B_ 32
#define N_ 512
#define D_ 768
#define H_ 12
#define HD_ 64
#define K_ 8
#define ND_ (N_ * D_)   // 393216

typedef __attribute__((address_space(1))) unsigned int as1_u32;
typedef __attribute__((address_space(3))) unsigned int as3_u32;

__device__ __forceinline__ void glds16(const void* g, void* l) {
  // async global->LDS, 16B/lane; LDS dest = wave-uniform base + lane*16
  __builtin_amdgcn_global_load_lds((as1_u32*)g, (as3_u32*)l, 16, 0, 0);
}

__device__ __forceinline__ f32x4 mfma16(bf16x8 a, bf16x8 b, f32x4 c) {
  return __builtin_amdgcn_mfma_f32_16x16x32_bf16(a, b, c, 0, 0, 0);
}

__device__ __forceinline__ bf16x8 addv8(bf16x8 a, bf16x8 b) {
  bf16x8 o;
#pragma unroll
  for (int j = 0; j < 8; ++j) o[j] = (bf16_t)((float)a[j] + (float)b[j]);
  return o;
}

// tid int32 or int64; int64 => word[1] (high half of elem0) == 0 (values 1..8).
__device__ __forceinline__ int seg_of(const int* tid, int b) {
  const bool is64 = (tid[1] == 0);
  int v = is64 ? (int)((const long long*)tid)[b] : tid[b];
  return v - 1;
}

// ---------------------------------------------------------------------------
// GEMM core (pure bf16, r13-verified): C[128x128] = A[128xK] * B^T[128xK],
// K=768, BK=32. Async glds staging, double-buffered, ONE barrier per K-iter.
// ---------------------------------------------------------------------------
__device__ __forceinline__ void gemm_core(const bf16_t* __restrict__ A,
                                          const bf16_t* __restrict__ Bw,
                                          char* smem, f32x4 (&acc)[4][4]) {
  const int t = threadIdx.x;
  const int lane = t & 63, w = t >> 6;
  const int quad = lane >> 4, l15 = lane & 15;
  const int r0 = t >> 2;         // staging row (chunk t); chunk t+256: +64
  const int c0e = (t & 3) * 8;   // staging k-element offset
  const int wbase = w * 1024;    // wave-uniform LDS base within a 4KB half
  const int mRow = (w >> 1) * 64, nCol = (w & 1) * 64;

  const bf16_t* ga0 = A + (size_t)r0 * D_ + c0e;
  const bf16_t* ga1 = A + (size_t)(r0 + 64) * D_ + c0e;
  const bf16_t* gb0 = Bw + (size_t)r0 * D_ + c0e;
  const bf16_t* gb1 = Bw + (size_t)(r0 + 64) * D_ + c0e;

  // preload iter 0 into buffer 0
  glds16(ga0, smem + wbase);
  glds16(ga1, smem + 4096 + wbase);
  glds16(gb0, smem + 8192 + wbase);
  glds16(gb1, smem + 12288 + wbase);

  for (int kb = 0; kb < 24; ++kb) {
    __syncthreads();  // vmcnt(0) drain: iter-kb glds complete; prev reads done
    char* cur = smem + (kb & 1) * 16384;
    char* nxt = smem + ((kb + 1) & 1) * 16384;
    if (kb < 23) {  // async-stage next slice; in flight during MFMA below
      const int ko = (kb + 1) * 32;
      glds16(ga0 + ko, nxt + wbase);
      glds16(ga1 + ko, nxt + 4096 + wbase);
      glds16(gb0 + ko, nxt + 8192 + wbase);
      glds16(gb1 + ko, nxt + 12288 + wbase);
    }
    bf16x8 af[4], bfr[4];
#pragma unroll
    for (int mt = 0; mt < 4; ++mt)
      af[mt] = *(const bf16x8*)(cur + (mRow + mt * 16 + l15) * 64 + quad * 16);
#pragma unroll
    for (int nt = 0; nt < 4; ++nt)
      bfr[nt] = *(const bf16x8*)(cur + 8192 + (nCol + nt * 16 + l15) * 64 +
                                 quad * 16);
#pragma unroll
    for (int mt = 0; mt < 4; ++mt)
#pragma unroll
      for (int nt = 0; nt < 4; ++nt)
        acc[mt][nt] = mfma16(af[mt], bfr[nt], acc[mt][nt]);
  }
}

__device__ __forceinline__ void zero_acc(f32x4 (&acc)[4][4]) {
  const f32x4 z = {0.f, 0.f, 0.f, 0.f};
#pragma unroll
  for (int a = 0; a < 4; ++a)
#pragma unroll
    for (int b = 0; b < 4; ++b) acc[a][b] = z;
}

// ---------------------------------------------------------------------------
// k_front roles (order = longest chain first):
//   blocks 0-35   : Wqc = Wq + Wq@Wc (f32 in, bf16 out; reg-staged MFMA,
//                   B=Wc staged TRANSPOSED through LDS; DOUBLE-buffered
//                   2x16KB, ONE barrier/iter; 6x6 tiles of 128^2, K=768)
//   blocks 36-38  : bq2[e] = sum_d Wq[e][d]*bc[d]  (f32)
//   blocks 39-230 : segmean + Xb emit
//   blocks 231-806: cvt of 4 weight matrices {Wq,Wk,Wv,Wo} (144 each, 2x
//                   data/block). Wc cvt DELETED (Wcb dead since r23 fold).
// ---------------------------------------------------------------------------
__global__ __launch_bounds__(256) void k_front(
    const float* __restrict__ x, const float* __restrict__ Wq,
    const float* __restrict__ Wk, const float* __restrict__ Wv,
    const float* __restrict__ Wc, const float* __restrict__ Wo,
    const float* __restrict__ bc, const int* __restrict__ tid,
    bf16_t* __restrict__ Xb, bf16_t* __restrict__ Wqb,
    bf16_t* __restrict__ Wkb, bf16_t* __restrict__ Wvb,
    bf16_t* __restrict__ Wob, bf16_t* __restrict__ Mx,
    bf16_t* __restrict__ Wqcb, float* __restrict__ bq2) {
  __shared__ alignas(16) char smem[32768];
  const int t = threadIdx.x;

  if (blockIdx.x < 36) {
    // ---- Wqc role: C[e][c] = sum_d Wq[e][d]*Wc[d][c]; out bf16(C + Wq) ----
    const int mblk = blockIdx.x / 6, nblk = blockIdx.x % 6;
    const int lane = t & 63, w = t >> 6;
    const int quad = lane >> 4, l15 = lane & 15;
    const int mRow = (w >> 1) * 64, nCol = (w & 1) * 64;
    const int ar = t >> 2, ac = (t & 3) * 8;
    const int bd = t >> 3, bc0 = (t & 7) * 16;
    const float* gA0 = Wq + (size_t)(mblk * 128 + ar) * D_ + ac;
    const float* gA1 = gA0 + (size_t)64 * D_;
    const float* gB = Wc + (size_t)bd * D_ + nblk * 128 + bc0;

    f32x4 a0[2], a1[2], bv[4];
    auto loadt = [&](int kb) {
      const int ko = kb * 32;
      a0[0] = *(const f32x4*)(gA0 + ko);
      a0[1] = *(const f32x4*)(gA0 + ko + 4);
      a1[0] = *(const f32x4*)(gA1 + ko);
      a1[1] = *(const f32x4*)(gA1 + ko + 4);
      const float* pb = gB + (size_t)ko * D_;
#pragma unroll
      for (int j = 0; j < 4; ++j) bv[j] = *(const f32x4*)(pb + j * 4);
    };
    auto writeb = [&](char* buf) {
      bf16x8 av0, av1;
#pragma unroll
      for (int j = 0; j < 4; ++j) {
        av0[j] = (bf16_t)a0[0][j]; av0[4 + j] = (bf16_t)a0[1][j];
        av1[j] = (bf16_t)a1[0][j]; av1[4 + j] = (bf16_t)a1[1][j];
      }
      *(bf16x8*)(buf + ar * 64 + (t & 3) * 16) = av0;
      *(bf16x8*)(buf + 4096 + ar * 64 + (t & 3) * 16) = av1;
      bf16_t* bl = (bf16_t*)(buf + 8192);
#pragma unroll
      for (int j = 0; j < 4; ++j)
#pragma unroll
        for (int jj = 0; jj < 4; ++jj)
          bl[(bc0 + j * 4 + jj) * 32 + bd] = (bf16_t)bv[j][jj];
    };

    f32x4 acc[4][4];
    zero_acc(acc);
    loadt(0);
    writeb(smem);      // buf0 <- tile 0
    loadt(1);          // regs <- tile 1
    __syncthreads();   // buf0 visible to all

    for (int kb = 0; kb < 24; ++kb) {
      char* cur = smem + (kb & 1) * 16384;
      if (kb < 23) {
        writeb(smem + ((kb + 1) & 1) * 16384);  // nxt <- tile kb+1 (regs);
        // safe: reads of nxt (iter kb-1) retired before the barrier crossed
        if (kb < 22) loadt(kb + 2);             // regs <- tile kb+2
      }
      bf16x8 af[4], bfr[4];
#pragma unroll
      for (int mt = 0; mt < 4; ++mt)
        af[mt] = *(const bf16x8*)(cur + (mRow + mt * 16 + l15) * 64 +
                                  quad * 16);
#pragma unroll
      for (int nt = 0; nt < 4; ++nt)
        bfr[nt] = *(const bf16x8*)(cur + 8192 + (nCol + nt * 16 + l15) * 64 +
                                   quad * 16);
#pragma unroll
      for (int mt = 0; mt < 4; ++mt)
#pragma unroll
        for (int nt = 0; nt < 4; ++nt)
          acc[mt][nt] = mfma16(af[mt], bfr[nt], acc[mt][nt]);
      if (kb < 23) __syncthreads();  // retire cur reads; nxt writes visible
    }
    const int mbase = mblk * 128 + mRow;
    const int nbase = nblk * 128 + nCol;
#pragma unroll
    for (int nt = 0; nt < 4; ++nt) {
      const int col = nbase + nt * 16 + l15;
#pragma unroll
      for (int mt = 0; mt < 4; ++mt)
#pragma unroll
        for (int r = 0; r < 4; ++r) {
          const int row = mbase + mt * 16 + quad * 4 + r;
          const size_t oi = (size_t)row * D_ + col;
          Wqcb[oi] = (bf16_t)(acc[mt][nt][r] + Wq[oi]);  // + identity term
        }
    }
    return;
  }

  if (blockIdx.x < 39) {
    // ---- bq2 role: bq2[e] = sum_d Wq[e][d] * bc[d] (f32) ----
    const int e = (blockIdx.x - 36) * 256 + t;
    const float* wr = Wq + (size_t)e * D_;
    float s = 0.f;
    for (int d = 0; d < D_; d += 4) {
      f32x4 wv = *(const f32x4*)(wr + d);
      f32x4 bv = *(const f32x4*)(bc + d);
#pragma unroll
      for (int j = 0; j < 4; ++j) s += wv[j] * bv[j];
    }
    bq2[e] = s;
    return;
  }

  if (blockIdx.x < 231) {
    // ---- segmean + Xb emit ----
    const size_t i = ((size_t)(blockIdx.x - 39) * 256 + t) * 8;
    float acc[K_][8];
    float cntk[K_];
#pragma unroll
    for (int k = 0; k < K_; ++k) {
      cntk[k] = 0.f;
#pragma unroll
      for (int j = 0; j < 8; ++j) acc[k][j] = 0.f;
    }
    const bool is64 = (tid[1] == 0);
    for (int b = 0; b < B_; ++b) {
      const int s = (is64 ? (int)((const long long*)tid)[b] : tid[b]) - 1;
      const float* p = x + (size_t)b * ND_ + i;
      f32x4 y0 = *(const f32x4*)p;
      f32x4 y1 = *(const f32x4*)(p + 4);
      bf16x8 xo;
#pragma unroll
      for (int j = 0; j < 4; ++j) {
        xo[j] = (bf16_t)y0[j];
        xo[4 + j] = (bf16_t)y1[j];
      }
      *(bf16x8*)(Xb + (size_t)b * ND_ + i) = xo;  // fused cvt-X
#pragma unroll
      for (int k = 0; k < K_; ++k) {
        const float msk = (s == k) ? 1.f : 0.f;
        cntk[k] += msk;
#pragma unroll
        for (int j = 0; j < 4; ++j) {
          acc[k][j] += msk * y0[j];
          acc[k][4 + j] += msk * y1[j];
        }
      }
    }
#pragma unroll
    for (int k = 0; k < K_; ++k) {
      const float inv = 1.f / fmaxf(cntk[k], 1.f);
      bf16x8 o;
#pragma unroll
      for (int j = 0; j < 8; ++j) o[j] = (bf16_t)(acc[k][j] * inv);
      *(bf16x8*)(Mx + (size_t)k * ND_ + i) = o;
    }
    return;
  }
  // ---- weight cvt role (4 matrices, 2x data per block: 144 blocks each) ----
  int bid = blockIdx.x - 231;
  const int wi = bid / 144;
  bid = bid % 144;
  const float* in = wi == 0 ? Wq : wi == 1 ? Wk : wi == 2 ? Wv : Wo;
  bf16_t* out = wi == 0 ? Wqb : wi == 1 ? Wkb : wi == 2 ? Wvb : Wob;
  const size_t i = ((size_t)bid * 256 + t) * 16;
#pragma unroll
  for (int h = 0; h < 2; ++h) {
    f32x4 a = *(const f32x4*)(in + i + h * 8);
    f32x4 b = *(const f32x4*)(in + i + h * 8 + 4);
    bf16x8 o;
#pragma unroll
    for (int j = 0; j < 4; ++j) {
      o[j] = (bf16_t)a[j];
      o[4 + j] = (bf16_t)b[j];
    }
    *(bf16x8*)(out + i + h * 8) = o;
  }
}

// ---------------------------------------------------------------------------
// k_mid: blocks 0-191 = Mq-role (Mq = Mx@Wqc^T + bq2, bf16 out, starts
//        first — its 24-iter latency chain hides under qkv);
//        blocks 192-2495 = fused QKV GEMM, r13-exact mapping on bid-192
//        (XCD-swizzled: 18 tiles of one X row-block on ONE XCD).
// __launch_bounds__(256,4): 4 blocks/CU (r22-measured win).
// ---------------------------------------------------------------------------
__global__ __launch_bounds__(256, 4) void k_mid(
    const bf16_t* __restrict__ X, const bf16_t* __restrict__ Wq,
    const bf16_t* __restrict__ Wk, const bf16_t* __restrict__ Wv,
    const float* __restrict__ bq, const float* __restrict__ bk,
    const float* __restrict__ bv, bf16_t* __restrict__ Q,
    bf16_t* __restrict__ Kb, bf16_t* __restrict__ V,
    const bf16_t* __restrict__ Mx, const bf16_t* __restrict__ Wqcb,
    const float* __restrict__ bq2, bf16_t* __restrict__ Mq) {
  __shared__ alignas(16) char smem[32768];
  const int lane = threadIdx.x & 63, w = threadIdx.x >> 6;
  const int quad = lane >> 4, l15 = lane & 15;

  if (blockIdx.x < 192) {
    // ---- Mq role: Mq = Mx @ Wqcb^T + bq2 ----
    const int mblk = blockIdx.x / 6, nblk = blockIdx.x % 6;
    f32x4 acc[4][4];
    zero_acc(acc);
    gemm_core(Mx + (size_t)mblk * 128 * D_, Wqcb + (size_t)nblk * 128 * D_,
              smem, acc);
    const int mbase = mblk * 128 + (w >> 1) * 64;
    const int nbase = nblk * 128 + (w & 1) * 64;
#pragma unroll
    for (int nt = 0; nt < 4; ++nt) {
      const int col = nbase + nt * 16 + l15;
      const float bb = bq2[col];
#pragma unroll
      for (int mt = 0; mt < 4; ++mt)
#pragma unroll
        for (int r = 0; r < 4; ++r) {
          const int row = mbase + mt * 16 + quad * 4 + r;
          Mq[(size_t)row * D_ + col] = (bf16_t)(acc[mt][nt][r] + bb);
        }
    }
    return;
  }

  // ---- QKV role (r13-exact on qbid) ----
  const int qbid = blockIdx.x - 192;
  const int xcd = qbid & 7, i = qbid >> 3;
  const int tile = i % 18, rowblk = (i / 18) * 8 + xcd;
  const int wsel = tile / 6, nb = tile % 6;
  const bf16_t* W = wsel == 0 ? Wq : wsel == 1 ? Wk : Wv;
  const float* bias = wsel == 0 ? bq : wsel == 1 ? bk : bv;
  bf16_t* Out = wsel == 0 ? Q : wsel == 1 ? Kb : V;

  f32x4 acc[4][4];
  zero_acc(acc);
  gemm_core(X + (size_t)rowblk * 128 * D_, W + (size_t)nb * 128 * D_, smem,
            acc);

  const int mbase = rowblk * 128 + (w >> 1) * 64;
  const int nbase = nb * 128 + (w & 1) * 64;
#pragma unroll
  for (int nt = 0; nt < 4; ++nt) {
    const int col = nbase + nt * 16 + l15;
    const float bb = bias[col];
#pragma unroll
    for (int mt = 0; mt < 4; ++mt)
#pragma unroll
      for (int r = 0; r < 4; ++r) {
        const int row = mbase + mt * 16 + quad * 4 + r;
        Out[(size_t)row * D_ + col] = (bf16_t)(acc[mt][nt][r] + bb);
      }
  }
}

// Plain GEMM: Out[Mx768] = A(bf16) @ W(bf16)^T (+bias f32) (+addA bf16).
// swz=1: flat grid M/128*6 blocks, XCD-swizzled. swz=0: 2D grid (M/128, 6).
__global__ __launch_bounds__(256) void k_gemm_plain(
    const bf16_t* __restrict__ A, const bf16_t* __restrict__ W,
    const float* __restrict__ bias, const bf16_t* __restrict__ addA,
    void* __restrict__ Out, int outF32, int swz) {
  __shared__ alignas(16) char smem[32768];
  int mblk, nblk;
  if (swz) {
    const int bid = blockIdx.x;
    const int xcd = bid & 7, i = bid >> 3;
    nblk = i % 6;
    mblk = (i / 6) * 8 + xcd;
  } else {
    mblk = blockIdx.x;
    nblk = blockIdx.y;
  }
  f32x4 acc[4][4];
  zero_acc(acc);
  gemm_core(A + (size_t)mblk * 128 * D_, W + (size_t)nblk * 128 * D_, smem,
            acc);
  const int lane = threadIdx.x & 63, w = threadIdx.x >> 6;
  const int quad = lane >> 4, l15 = lane & 15;
  const int mbase = mblk * 128 + (w >> 1) * 64;
  const int nbase = nblk * 128 + (w & 1) * 64;
#pragma unroll
  for (int nt = 0; nt < 4; ++nt) {
    const int col = nbase + nt * 16 + l15;
    const float bb = bias ? bias[col] : 0.f;
#pragma unroll
    for (int mt = 0; mt < 4; ++mt)
#pragma unroll
      for (int r = 0; r < 4; ++r) {
        const int row = mbase + mt * 16 + quad * 4 + r;
        float v = acc[mt][nt][r] + bb;
        if (addA) v += (float)addA[(size_t)row * D_ + col];
        const size_t oi = (size_t)row * D_ + col;
        if (outF32) ((float*)Out)[oi] = v;
        else ((bf16_t*)Out)[oi] = (bf16_t)v;
      }
  }
}

// ---------------------------------------------------------------------------
// Flash attention per (b,h): Out = softmax(Q' @ K'^T / 8) @ V   (EXACT r13)
//   addq==1: queries = Qp + Madd[seg];  addq==2: keys = Kp + Madd[seg]
// No max-subtraction; deferred l-reduction; sigma-permuted keys; K/V register
// prefetch. grid = (4, B*H).
// ---------------------------------------------------------------------------
__global__ __launch_bounds__(256) void k_attn(const bf16_t* __restrict__ Qp,
                                              const bf16_t* __restrict__ Kp,
                                              const bf16_t* __restrict__ Vp,
                                              const bf16_t* __restrict__ Madd,
                                              const int* __restrict__ tid,
                                              bf16_t* __restrict__ Op,
                                              int addq) {
  __shared__ alignas(16) __bf16 Kt[64][72];
  __shared__ alignas(16) __bf16 Vt[64][72];
  __shared__ alignas(16) __bf16 Pl[4][32][72];

  const int lane = threadIdx.x & 63, w = threadIdx.x >> 6;
  const int quad = lane >> 4, l15 = lane & 15;
  const int b = blockIdx.y / H_, h = blockIdx.y % H_;
  const int q0 = blockIdx.x * 128 + w * 32;
  const size_t base = (size_t)b * ND_ + h * HD_;
  const float C = 0.18033688011112042f;  // log2(e) / sqrt(HD)
  const int sg = seg_of(tid, b);
  const bf16_t* Mh = Madd + (size_t)sg * ND_ + h * HD_;

  bf16x8 aq[2][2];
#pragma unroll
  for (int mt = 0; mt < 2; ++mt)
#pragma unroll
    for (int ks = 0; ks < 2; ++ks) {
      const size_t off = (size_t)(q0 + mt * 16 + l15) * D_ + ks * 32 + quad * 8;
      bf16x8 q = *(const bf16x8*)(Qp + base + off);
      if (addq == 1) q = addv8(q, *(const bf16x8*)(Mh + off));
      aq[mt][ks] = q;
    }

  f32x4 O[2][4];
  float lacc[2][4];
  {
    const f32x4 z = {0.f, 0.f, 0.f, 0.f};
#pragma unroll
    for (int mt = 0; mt < 2; ++mt)
#pragma unroll
      for (int nt = 0; nt < 4; ++nt) O[mt][nt] = z;
#pragma unroll
    for (int mt = 0; mt < 2; ++mt)
#pragma unroll
      for (int r = 0; r < 4; ++r) lacc[mt][r] = 0.f;
  }

  const int sr = threadIdx.x >> 2, sc = threadIdx.x & 3;
  const int sig_sr = ((sr & 15) << 2) | (sr >> 4);  // sigma-permuted V column

  bf16x8 kr[2], vr[2];
#pragma unroll
  for (int half = 0; half < 2; ++half) {
    const int cc = sc + half * 4;
    const size_t off = (size_t)sr * D_ + cc * 8;
    bf16x8 kv = *(const bf16x8*)(Kp + base + off);
    if (addq == 2) kv = addv8(kv, *(const bf16x8*)(Mh + off));
    kr[half] = kv;
    vr[half] = *(const bf16x8*)(Vp + base + off);
  }

  for (int c0 = 0; c0 < N_; c0 += 64) {
    __syncthreads();
#pragma unroll
    for (int half = 0; half < 2; ++half) {
      const int cc = sc + half * 4;
      *(bf16x8*)(&Kt[sr][cc * 8]) = kr[half];
#pragma unroll
      for (int j = 0; j < 8; ++j) Vt[cc * 8 + j][sig_sr] = vr[half][j];
    }
    __syncthreads();

    if (c0 + 64 < N_) {
#pragma unroll
      for (int half = 0; half < 2; ++half) {
        const int cc = sc + half * 4;
        const size_t off = (size_t)(c0 + 64 + sr) * D_ + cc * 8;
        bf16x8 kv = *(const bf16x8*)(Kp + base + off);
        if (addq == 2) kv = addv8(kv, *(const bf16x8*)(Mh + off));
        kr[half] = kv;
        vr[half] = *(const bf16x8*)(Vp + base + off);
      }
    }

    f32x4 S[2][4];
    {
      const f32x4 z = {0.f, 0.f, 0.f, 0.f};
#pragma unroll
      for (int mt = 0; mt < 2; ++mt)
#pragma unroll
        for (int nt = 0; nt < 4; ++nt) S[mt][nt] = z;
    }
#pragma unroll
    for (int ks = 0; ks < 2; ++ks) {
      bf16x8 bk[4];
#pragma unroll
      for (int nt = 0; nt < 4; ++nt)
        bk[nt] = *(const bf16x8*)(&Kt[nt * 16 + l15][ks * 32 + quad * 8]);
#pragma unroll
      for (int mt = 0; mt < 2; ++mt)
#pragma unroll
        for (int nt = 0; nt < 4; ++nt)
          S[mt][nt] = mfma16(aq[mt][ks], bk[nt], S[mt][nt]);
    }

#pragma unroll
    for (int mt = 0; mt < 2; ++mt)
#pragma unroll
      for (int r = 0; r < 4; ++r) {
        bf16x4 pk;
#pragma unroll
        for (int nt = 0; nt < 4; ++nt) {
          const float p = exp2f(S[mt][nt][r] * C);
          lacc[mt][r] += p;
          pk[nt] = (bf16_t)p;
        }
        *(bf16x4*)(&Pl[w][mt * 16 + quad * 4 + r][l15 * 4]) = pk;
      }

#pragma unroll
    for (int ks2 = 0; ks2 < 2; ++ks2) {
      bf16x8 ap[2], bv[4];
#pragma unroll
      for (int mt = 0; mt < 2; ++mt)
        ap[mt] = *(const bf16x8*)(&Pl[w][mt * 16 + l15][ks2 * 32 + quad * 8]);
#pragma unroll
      for (int nt2 = 0; nt2 < 4; ++nt2)
        bv[nt2] = *(const bf16x8*)(&Vt[nt2 * 16 + l15][ks2 * 32 + quad * 8]);
#pragma unroll
      for (int mt = 0; mt < 2; ++mt)
#pragma unroll
        for (int nt2 = 0; nt2 < 4; ++nt2)
          O[mt][nt2] = mfma16(ap[mt], bv[nt2], O[mt][nt2]);
    }
  }

#pragma unroll
  for (int mt = 0; mt < 2; ++mt)
#pragma unroll
    for (int r = 0; r < 4; ++r) {
      float l = lacc[mt][r];
#pragma unroll
      for (int d = 1; d < 16; d <<= 1) l += __shfl_xor(l, d);
      const float inv = 1.f / l;
      const size_t row = base + (size_t)(q0 + mt * 16 + quad * 4 + r) * D_;
#pragma unroll
      for (int nt2 = 0; nt2 < 4; ++nt2)
        Op[row + nt2 * 16 + l15] = (bf16_t)(O[mt][nt2][r] * inv);
    }
}

// Fallback: zero d_out (f32 extent). Fingerprint: absmax == max|ref|.
__global__ __launch_bounds__(256) void k_zero(float* __restrict__ out) {
  const size_t i = ((size_t)blockIdx.x * 256 + threadIdx.x) * 8;
  f32x4 z = {0.f, 0.f, 0.f, 0.f};
  *(f32x4*)(out + i) = z;
  *(f32x4*)(out + i + 4) = z;
}

// ---------------------------------------------------------------------------
extern "C" void kernel_launch(void* const* d_in, const int* in_sizes, int n_in,
                              void* d_out, int out_size, void* d_ws,
                              size_t ws_size, hipStream_t stream) {
  const float* x  = (const float*)d_in[0];
  const int*  tid = (const int*)d_in[1];
  const float* Wq = (const float*)d_in[2];
  const float* bq = (const float*)d_in[3];
  const float* Wk = (const float*)d_in[4];
  const float* bk = (const float*)d_in[5];
  const float* Wv = (const float*)d_in[6];
  const float* bv = (const float*)d_in[7];
  const float* Wo = (const float*)d_in[8];
  const float* bo = (const float*)d_in[9];
  const float* Wc = (const float*)d_in[10];
  const float* bc = (const float*)d_in[11];

  const size_t SZ  = (size_t)B_ * ND_ * sizeof(bf16_t);   // 25165824
  const size_t MSZ = (size_t)K_ * ND_ * sizeof(bf16_t);   // 6291456
  const size_t WSZ = (size_t)D_ * D_ * sizeof(bf16_t);    // 1179648
  if (ws_size < 3 * SZ + MSZ + 5 * WSZ) {  // diagnosable fallback
    k_zero<<<6144, 256, 0, stream>>>((float*)d_out);
    return;
  }

  char* ws = (char*)d_ws;
  bf16_t* Qb  = (bf16_t*)(ws);
  bf16_t* Kb  = (bf16_t*)(ws + SZ);
  bf16_t* Vb  = (bf16_t*)(ws + 2 * SZ);
  bf16_t* Mq  = (bf16_t*)(ws + 3 * SZ);
  bf16_t* Wqb = (bf16_t*)(ws + 3 * SZ + MSZ);
  bf16_t* Wkb = (bf16_t*)(ws + 3 * SZ + MSZ + WSZ);
  bf16_t* Wvb = (bf16_t*)(ws + 3 * SZ + MSZ + 2 * WSZ);
  bf16_t* Wob = (bf16_t*)(ws + 3 * SZ + MSZ + 4 * WSZ);
  // merge-safe aliasing (all in d_out's first half = VT region, dead
  // before attn1 writes VT):
  bf16_t* Wqcb = (bf16_t*)d_out;                             // [0, 1.2MB)
  float*  bq2  = (float*)((char*)d_out + 2 * 1024 * 1024);   // [2MB, +3KB)
  bf16_t* Mx   = (bf16_t*)((char*)d_out + 8 * 1024 * 1024);  // [8, 14.3MB)
  bf16_t* VT   = (bf16_t*)d_out;   // bf16 scratch: first half of d_out
  bf16_t* Xb   = (bf16_t*)d_out + (size_t)B_ * ND_;  // second half of d_out
  bf16_t* CTX  = Kb;               // K dead after stage-1 attention

  // 1) Wqc (0-35) + bq2 (36-38) + segmean+XbEmit (39-230) + wcvt (231-806)
  k_front<<<807, 256, 0, stream>>>(x, Wq, Wk, Wv, Wc, Wo, bc, tid, Xb, Wqb,
                                   Wkb, Wvb, Wob, Mx, Wqcb, bq2);
  // 2) Mq = Mx@Wqc^T + bq2 (blocks 0-191) + QKV (192-2495)
  k_mid<<<2496, 256, 0, stream>>>(Xb, Wqb, Wkb, Wvb, bq, bk, bv, Qb, Kb, Vb,
                                  Mx, Wqcb, bq2, Mq);
  // 3,4) dual-stage attention
  k_attn<<<dim3(4, B_ * H_), 256, 0, stream>>>(Qb, Kb, Vb, Mq, tid, VT, 1);
  k_attn<<<dim3(4, B_ * H_), 256, 0, stream>>>(Qb, Qb, VT, Mq, tid, CTX, 2);
  // 5) out = CTX @ Wo^T + bo
  k_gemm_plain<<<768, 256, 0, stream>>>(CTX, Wob, bo, nullptr, d_out, 1, 1);
}